// Round 11
// baseline (360.609 us; speedup 1.0000x reference)
//
#include <hip/hip_runtime.h>
#include <hip/hip_bf16.h>

#define NB 64
#define S_ 1024
#define D_ 128

typedef __attribute__((ext_vector_type(8))) short bf16x8;
typedef __attribute__((ext_vector_type(4))) float f32x4;
typedef __attribute__((ext_vector_type(4))) unsigned int u32x4;

// Fragment-tiled layout: operands stored as 16-row x 32-k panels of 1KB,
// element (r,k) at short-offset (((k>>3)&3)*16 + (r&15))*8 + (k&7) ==
// lane*8 + j in MFMA A/B fragment order -> a wave fragment load/store is
// base + lane*16B: one coalesced 1KB transaction.

__device__ __forceinline__ unsigned short f2bf(float f) {
  __hip_bfloat16 h = __float2bfloat16(f);
  return __builtin_bit_cast(unsigned short, h);
}

__device__ __forceinline__ void async_copy16(const void* g, void* l) {
  __builtin_amdgcn_global_load_lds(
      (const __attribute__((address_space(1))) unsigned int*)g,
      (__attribute__((address_space(3))) unsigned int*)l, 16, 0, 0);
}

// Device-scope (MALL write-through) 16B store: publishes producer data so
// consumers on ANY XCD see it after the paired atomic flag (Guideline 16).
__device__ __forceinline__ void store16_dev(void* p, bf16x8 v) {
  u32x4 d = __builtin_bit_cast(u32x4, v);
  asm volatile("global_store_dwordx4 %0, %1, off sc1" ::"v"(p), "v"(d)
               : "memory");
}

// Bounded spin on MALL-coherent relaxed atomics (R5/R6-proven; worst case
// ~tens of ms then loud failure). Ends with a block barrier -> also serves
// as the LDS-protection barrier at panel boundaries.
__device__ __forceinline__ void spin_mask(unsigned* p, unsigned need) {
  if (threadIdx.x == 0) {
    int guard = 0;
    while ((__hip_atomic_load(p, __ATOMIC_RELAXED, __HIP_MEMORY_SCOPE_AGENT) &
            need) != need) {
      __builtin_amdgcn_s_sleep(1);
      if (++guard > 2000000) break;
    }
  }
  __syncthreads();
  asm volatile("" ::: "memory");
}

// Drain own stores to coherence point, then one flag-set per block.
__device__ __forceinline__ void publish_bit(unsigned* p, unsigned bit) {
  asm volatile("s_waitcnt vmcnt(0)" ::: "memory");
  __syncthreads();
  if (threadIdx.x == 0)
    __hip_atomic_fetch_or(p, bit, __ATOMIC_RELAXED, __HIP_MEMORY_SCOPE_AGENT);
}

// ---- K1: W-pack (all 512 blocks) + per-batch stats partials (blocks<256) ---
// Kernel boundary publishes W1f/W2f AND the stats sums (atomicAdd, MALL) to
// the mega kernel — no in-kernel stats spin needed anywhere.
__global__ __launch_bounds__(256) void prep_kernel(
    const float* __restrict__ x, const float* __restrict__ W1,
    const float* __restrict__ W2, float* __restrict__ stats,
    unsigned short* __restrict__ W1f, unsigned short* __restrict__ W2f) {
  __shared__ float2 w4[4];
  const int blk = blockIdx.x;          // 0..511
  const int t = threadIdx.x;
  const int wave = t >> 6, lane = t & 63;
  const int quad = lane >> 4, l16 = lane & 15;

  if (blk < 256) {                     // stats: batch b, row-quarter sl
    const int b = blk >> 2, sl = blk & 3;
    const float4* xb =
        (const float4*)(x + (size_t)b * (S_ * D_) + (size_t)sl * (256 * D_));
    float s = 0.f, q = 0.f;
#pragma unroll
    for (int i = 0; i < 32; ++i) {
      float4 v = xb[i * 256 + t];
      s += v.x + v.y + v.z + v.w;
      q += v.x * v.x + v.y * v.y + v.z * v.z + v.w * v.w;
    }
#pragma unroll
    for (int o = 32; o > 0; o >>= 1) {
      s += __shfl_down(s, o, 64);
      q += __shfl_down(q, o, 64);
    }
    if (lane == 0) w4[wave] = make_float2(s, q);
    __syncthreads();
    if (t == 0) {
      float ss = 0.f, qq = 0.f;
#pragma unroll
      for (int i = 0; i < 4; ++i) { ss += w4[i].x; qq += w4[i].y; }
      __hip_atomic_fetch_add(stats + (size_t)b * 32 + 0, ss, __ATOMIC_RELAXED,
                             __HIP_MEMORY_SCOPE_AGENT);
      __hip_atomic_fetch_add(stats + (size_t)b * 32 + 1, qq, __ATOMIC_RELAXED,
                             __HIP_MEMORY_SCOPE_AGENT);
    }
  }
  // W-pack: 4096 fragment-chunks over 512 blocks x 8 wave-units
#pragma unroll
  for (int rep = 0; rep < 2; ++rep) {
    const int u = blk * 8 + wave * 2 + rep;
    const int f = u & 2047;
    const int p = f >> 5, c = f & 31;
    const int r = p * 16 + l16;
    const int k0 = c * 32 + quad * 8;
    const float* wsrc = ((u >> 11) ? W2 : W1) + (size_t)r * 1024 + k0;
    float4 a0 = ((const float4*)wsrc)[0];
    float4 a1 = ((const float4*)wsrc)[1];
    float av[8] = {a0.x, a0.y, a0.z, a0.w, a1.x, a1.y, a1.z, a1.w};
    bf16x8 o;
#pragma unroll
    for (int jj = 0; jj < 8; ++jj)
      o[jj] = (short)f2bf((k0 + jj <= r) ? av[jj] : 0.f);
    unsigned short* dstp = ((u >> 11) ? W2f : W1f) +
                           ((size_t)p * 32 + c) * 512 + lane * 8;
    *(bf16x8*)dstp = o;
  }
}

// ------------- causal batched GEMM phase: 16KB half-panel LDS A -------------
// BM=64 (t), BN=128 (d); wave owns 64m x 32n (VGPR ~56, fits the 64-cap of
// launch_bounds(256,8) — R9-measured). A staged per 4-chunk half-panel via
// global_load_lds; B direct global->VGPR, depth-4 rolling prefetch.
// PROGRESSIVE waits (R8-proven): panel hp needs producer bits covering
// chunks .. hp*4+7 (panel + prefetch lookahead); the spin's syncthreads is
// also the LDS-protect barrier. Entry spin covers chunks 0..7.
template <bool HSWISH>
__device__ __forceinline__ void gemm_phase(
    unsigned short* ldsA, const int b, const int mt, unsigned* flags,
    const unsigned short* __restrict__ Af, const unsigned short* __restrict__ Bf,
    unsigned short* __restrict__ Uf, const float* __restrict__ Xres,
    float* __restrict__ Out) {
  const int t = threadIdx.x;
  const int wave = t >> 6, lane = t & 63;
  const int quad = lane >> 4, l16 = lane & 15;
  const int row0 = mt * 64;

  const int cend = 2 * (mt + 1);       // active 32-k chunks (even, 2..32)
  const int nhp = (cend + 3) >> 2;     // 4-chunk half-panels (16KB)

  const unsigned short* Ab = Af + (size_t)mt * 4 * 32 * 512;
  const unsigned short* Bb = Bf + (size_t)b * (D_ * S_);

  {                                    // entry: producers of chunks 0..7
    const int C = (cend - 1 < 7) ? (cend - 1) : 7;
    spin_mask(flags, (2u << (C >> 1)) - 1u);
  }

  f32x4 acc[4][2] = {};
  bf16x8 Bp[4][2];
#pragma unroll
  for (int g = 0; g < 4; ++g) {
    const int gg = (g < cend) ? g : 0;
#pragma unroll
    for (int jj = 0; jj < 2; ++jj)
      Bp[g][jj] = *(const bf16x8*)(Bb + ((size_t)(wave * 2 + jj) * 32 + gg) * 512 + lane * 8);
  }

  for (int hp = 0; hp < nhp; ++hp) {
    if (hp) {                          // dep wait + LDS-protect barrier
      const int C = (cend - 1 < hp * 4 + 7) ? (cend - 1) : (hp * 4 + 7);
      spin_mask(flags, (2u << (C >> 1)) - 1u);
    }
    const int rem = cend - hp * 4;
    if (wave < rem) {                  // wave-uniform gate; stage chunk hp*4+wave
#pragma unroll
      for (int jc = 0; jc < 4; ++jc)
        async_copy16(Ab + ((size_t)jc * 32 + hp * 4 + wave) * 512 + lane * 8,
                     ldsA + ((size_t)jc * 256 + t) * 8);
    }
    __syncthreads();                   // drains vmcnt; half-panel ready
#pragma unroll
    for (int c = 0; c < 4; ++c) {
      const int g = hp * 4 + c;
      if (g < cend) {
        bf16x8 af[4];
#pragma unroll
        for (int i = 0; i < 4; ++i)
          af[i] = *(const bf16x8*)(ldsA + i * 2048 + c * 512 + lane * 8);
        __builtin_amdgcn_s_setprio(1);
#pragma unroll
        for (int i = 0; i < 4; ++i)
#pragma unroll
          for (int jj = 0; jj < 2; ++jj)
            acc[i][jj] = __builtin_amdgcn_mfma_f32_16x16x32_bf16(
                af[i], Bp[c][jj], acc[i][jj], 0, 0, 0);
        __builtin_amdgcn_s_setprio(0);
      }
      const int gn = (g + 4 < cend) ? (g + 4) : 0;
#pragma unroll
      for (int jj = 0; jj < 2; ++jj)
        Bp[c][jj] = *(const bf16x8*)(
            Bb + ((size_t)(wave * 2 + jj) * 32 + gn) * 512 + lane * 8);
    }
  }

  if (HSWISH) {
    // transpose in TWO 64-col halves (scr = 64x72 shorts = 9.2KB of 16KB LDS)
    unsigned short* scr = ldsA;
#pragma unroll
    for (int half = 0; half < 2; ++half) {
      __syncthreads();                 // prior readers (staging / half 0) done
      if ((wave >> 1) == half) {       // waves 2h,2h+1 own d-cols 64h..64h+63
#pragma unroll
        for (int i = 0; i < 4; ++i)
#pragma unroll
          for (int jj = 0; jj < 2; ++jj) {
            ushort4 pk;
            float v0 = acc[i][jj][0], v1 = acc[i][jj][1], v2 = acc[i][jj][2],
                  v3 = acc[i][jj][3];
            pk.x = f2bf(v0 * fminf(fmaxf(v0 + 3.f, 0.f), 6.f) * (1.f / 6.f));
            pk.y = f2bf(v1 * fminf(fmaxf(v1 + 3.f, 0.f), 6.f) * (1.f / 6.f));
            pk.z = f2bf(v2 * fminf(fmaxf(v2 + 3.f, 0.f), 6.f) * (1.f / 6.f));
            pk.w = f2bf(v3 * fminf(fmaxf(v3 + 3.f, 0.f), 6.f) * (1.f / 6.f));
            const int nl = (wave & 1) * 32 + jj * 16 + l16;  // d within half
            const int m0 = i * 16 + quad * 4;                // t within tile
            *(ushort4*)(scr + nl * 72 + m0) = pk;
          }
      }
      __syncthreads();                 // half's scr complete
      unsigned short* gU = Uf + (size_t)b * (D_ * S_);
#pragma unroll
      for (int ff = 0; ff < 2; ++ff) { // 8 frags of this half over 4 waves
        const int f = wave * 2 + ff;
        const int p2l = f >> 1, cl = f & 1;
        const int dl = p2l * 16 + l16;
        const int tb = cl * 32 + quad * 8;
        bf16x8 v = *(const bf16x8*)(scr + dl * 72 + tb);
        store16_dev(gU + ((size_t)(half * 4 + p2l) * 32 + mt * 2 + cl) * 512 +
                        lane * 8,
                    v);
      }
    }
  } else {
    float* gO = Out + (size_t)b * S_ * D_;
    const float* gX = Xres + (size_t)b * S_ * D_;
#pragma unroll
    for (int i = 0; i < 4; ++i) {
      const int mrow0 = row0 + i * 16 + quad * 4;
#pragma unroll
      for (int jj = 0; jj < 2; ++jj) {
        const int col = wave * 32 + jj * 16 + l16;
#pragma unroll
        for (int r = 0; r < 4; ++r) {
          const int addr = (mrow0 + r) * D_ + col;
          gO[addr] = gX[addr] + acc[i][jj][r];
        }
      }
    }
  }
}

// ---- K2 mega (grid 2048, 8 blocks/CU): producer/consumer phase overlap -----
// Group A (bi<1024): mu/rs from K1-published sums (no spin) -> norm own
// s-tile -> hTf sc1 + h-bit -> gemm1 (progressive h-waits) -> uTf sc1 +
// u-bit, exit. Group B (bi>=1024): gemm2 with progressive u-waits -> out.
// All 2048 blocks co-resident (16.96KB LDS x 8 = 135.7KB; 32 waves/CU; VGPR
// <=64 by launch_bounds — R9 measured 56 for this gemm shape). B-blocks
// sleep on u-bits while A-blocks compute -> gemm2 overlaps gemm1's tail.
// Per-CU balance: resident set {cu+256k} gives both groups the same
// sum(cend)=68 mt-multiset.
__global__ __launch_bounds__(256, 8) void mega_kernel(
    const float* __restrict__ x, const float* __restrict__ ln_w,
    const float* __restrict__ ln_b, const unsigned short* __restrict__ W1f,
    const unsigned short* __restrict__ W2f, float* __restrict__ stats,
    unsigned short* __restrict__ hTf, unsigned short* __restrict__ uTf,
    float* __restrict__ out) {
  __shared__ __align__(16) unsigned short smem[8480];   // 16.96 KB

  const int bi = blockIdx.x;           // 0..2047
  const int grp = bi >> 10;            // 0 = norm+gemm1, 1 = gemm2
  const int inner = bi & 1023;
  const int xcd = inner & 7;           // perf heuristic only (L2 locality)
  const int slot = inner >> 3;
  const int b = xcd * 8 + (slot & 7);
  const int j = slot >> 3;
  const int mt = (j < 8) ? j : (j ^ 3);

  const int t = threadIdx.x;
  const int wave = t >> 6, lane = t & 63;
  const int quad = lane >> 4, l16 = lane & 15;

  float* sb = stats + (size_t)b * 32;  // 128B/batch slot
  unsigned* hmp = (unsigned*)sb + 4;
  unsigned* ump = (unsigned*)sb + 6;

  if (grp == 0) {
    // ---------- mu/rs from K1 sums (boundary-published, no spin) ------------
    const float inv = 1.0f / (S_ * D_);
    const float mu = sb[0] * inv;
    const float rs = rsqrtf(sb[1] * inv - mu * mu + 1e-5f);

    // ---------- normalize own s-tile + LDS [s][d+4pad] transpose ------------
    {
      unsigned short* lds = smem;      // 64*132 = 8448 shorts of 8480
      const float4* xb = (const float4*)(x + ((size_t)b * S_ + mt * 64) * D_);
      const float4* wb = (const float4*)(ln_w + (size_t)(mt * 64) * D_);
      const float4* bv4 = (const float4*)(ln_b + (size_t)(mt * 64) * D_);
#pragma unroll
      for (int rr = 0; rr < 8; ++rr) {
        const int f = rr * 256 + t;
        const int srow = f >> 5;
        const int c4 = f & 31;
        float4 xv = xb[f];
        float4 wv = wb[f];
        float4 bvv = bv4[f];
        ushort4 o;
        o.x = f2bf((xv.x - mu) * rs * wv.x + bvv.x);
        o.y = f2bf((xv.y - mu) * rs * wv.y + bvv.y);
        o.z = f2bf((xv.z - mu) * rs * wv.z + bvv.z);
        o.w = f2bf((xv.w - mu) * rs * wv.w + bvv.w);
        *(ushort4*)(lds + srow * 132 + c4 * 4) = o;
      }
      __syncthreads();
      unsigned short* outp = hTf + (size_t)b * (D_ * S_);
      const int cg0 = mt * 2;
#pragma unroll
      for (int ff = 0; ff < 4; ++ff) {
        const int f = wave * 4 + ff;   // 16 fragments per block
        const int p = f >> 1, cl = f & 1;
        const int d = p * 16 + l16;
        const int sbase = cl * 32 + quad * 8;
        bf16x8 v;
#pragma unroll
        for (int jj = 0; jj < 8; ++jj)
          v[jj] = (short)lds[(sbase + jj) * 132 + d];
        store16_dev(outp + ((size_t)p * 32 + cg0 + cl) * 512 + lane * 8, v);
      }
    }
    publish_bit(hmp, 1u << mt);

    // ---------- gemm1: u = hardswish(W1c @ h), progressive h-waits ----------
    gemm_phase<true>(smem, b, mt, hmp, W1f, hTf, uTf, nullptr, nullptr);
    publish_bit(ump, 1u << mt);
  } else {
    // ---------- gemm2: out = x + W2c @ u, progressive u-waits ---------------
    gemm_phase<false>(smem, b, mt, ump, W2f, uTf, nullptr, x, out);
  }
}

extern "C" void kernel_launch(void* const* d_in, const int* in_sizes, int n_in,
                              void* d_out, int out_size, void* d_ws, size_t ws_size,
                              hipStream_t stream) {
  const float* x = (const float*)d_in[0];
  const float* ln_w = (const float*)d_in[1];
  const float* ln_b = (const float*)d_in[2];
  const float* W1 = (const float*)d_in[3];
  const float* W2 = (const float*)d_in[4];
  float* out = (float*)d_out;

  char* ws = (char*)d_ws;
  float* stats = (float*)ws;                                 // 8 KiB (64x128B)
  unsigned short* W1f = (unsigned short*)(ws + 16384);       // 2 MiB
  unsigned short* W2f = W1f + (size_t)S_ * S_;               // 2 MiB
  unsigned short* hTf = W2f + (size_t)S_ * S_;               // 16 MiB
  unsigned short* uTf = hTf + (size_t)NB * D_ * S_;          // 16 MiB

  hipMemsetAsync(stats, 0, 8192, stream);   // zero stats/flag slots
  prep_kernel<<<512, 256, 0, stream>>>(x, W1, W2, stats, W1f, W2f);
  mega_kernel<<<2048, 256, 0, stream>>>(x, ln_w, ln_b, W1f, W2f, stats,
                                        hTf, uTf, out);
}

// Round 12
// 133.563 us; speedup vs baseline: 2.6999x; 2.6999x over previous
//
#include <hip/hip_runtime.h>
#include <hip/hip_bf16.h>

#define NB 64
#define S_ 1024
#define D_ 128

typedef __attribute__((ext_vector_type(8))) short bf16x8;
typedef __attribute__((ext_vector_type(4))) float f32x4;
typedef __attribute__((ext_vector_type(4))) unsigned int u32x4;

// Fragment-tiled layout: operands stored as 16-row x 32-k panels of 1KB,
// element (r,k) at short-offset (((k>>3)&3)*16 + (r&15))*8 + (k&7) ==
// lane*8 + j in MFMA A/B fragment order -> a wave fragment load/store is
// base + lane*16B: one coalesced 1KB transaction.

__device__ __forceinline__ unsigned short f2bf(float f) {
  __hip_bfloat16 h = __float2bfloat16(f);
  return __builtin_bit_cast(unsigned short, h);
}

__device__ __forceinline__ void async_copy16(const void* g, void* l) {
  __builtin_amdgcn_global_load_lds(
      (const __attribute__((address_space(1))) unsigned int*)g,
      (__attribute__((address_space(3))) unsigned int*)l, 16, 0, 0);
}

// Device-scope (MALL write-through) 16B store: publishes producer data so
// consumers on ANY XCD see it after the paired atomic flag (Guideline 16).
__device__ __forceinline__ void store16_dev(void* p, bf16x8 v) {
  u32x4 d = __builtin_bit_cast(u32x4, v);
  asm volatile("global_store_dwordx4 %0, %1, off sc1" ::"v"(p), "v"(d)
               : "memory");
}

// Bounded spin on MALL-coherent relaxed atomics (R5/R6-proven; worst case
// ~tens of ms then loud failure, never a GPU hang).
__device__ __forceinline__ void spin_mask(unsigned* p, unsigned need) {
  if (threadIdx.x == 0) {
    int guard = 0;
    while ((__hip_atomic_load(p, __ATOMIC_RELAXED, __HIP_MEMORY_SCOPE_AGENT) &
            need) != need) {
      __builtin_amdgcn_s_sleep(1);
      if (++guard > 2000000) break;
    }
  }
  __syncthreads();
  asm volatile("" ::: "memory");
}

// Drain own stores to coherence point, then one flag-set per block.
__device__ __forceinline__ void publish_bit(unsigned* p, unsigned bit) {
  asm volatile("s_waitcnt vmcnt(0)" ::: "memory");
  __syncthreads();
  if (threadIdx.x == 0)
    __hip_atomic_fetch_or(p, bit, __ATOMIC_RELAXED, __HIP_MEMORY_SCOPE_AGENT);
}

// ---- K1: W-pack (1024 blocks, one 1KB chunk/wave) + stats (blocks < 256) ---
// Kernel boundary publishes W1f/W2f AND the per-batch stats sums (atomicAdd
// at MALL; R11 validated atomicAdd -> boundary -> plain-read). Mega then
// needs NO stats pass and NO cnt spin — one fewer 32MB x-pass on its
// critical path; the stats read here overlaps the W-pack streaming.
__global__ __launch_bounds__(256) void prep_kernel(
    const float* __restrict__ x, const float* __restrict__ W1,
    const float* __restrict__ W2, float* __restrict__ stats,
    unsigned short* __restrict__ W1f, unsigned short* __restrict__ W2f) {
  __shared__ float2 w4[4];
  const int blk = blockIdx.x;          // 0..1023
  const int t = threadIdx.x;
  const int wave = t >> 6, lane = t & 63;
  const int quad = lane >> 4, l16 = lane & 15;

  if (blk < 256) {                     // stats: batch b, row-quarter sl
    const int b = blk >> 2, sl = blk & 3;
    const float4* xb =
        (const float4*)(x + (size_t)b * (S_ * D_) + (size_t)sl * (256 * D_));
    float s = 0.f, q = 0.f;
#pragma unroll
    for (int i = 0; i < 32; ++i) {
      float4 v = xb[i * 256 + t];
      s += v.x + v.y + v.z + v.w;
      q += v.x * v.x + v.y * v.y + v.z * v.z + v.w * v.w;
    }
#pragma unroll
    for (int o = 32; o > 0; o >>= 1) {
      s += __shfl_down(s, o, 64);
      q += __shfl_down(q, o, 64);
    }
    if (lane == 0) w4[wave] = make_float2(s, q);
    __syncthreads();
    if (t == 0) {
      float ss = 0.f, qq = 0.f;
#pragma unroll
      for (int i = 0; i < 4; ++i) { ss += w4[i].x; qq += w4[i].y; }
      __hip_atomic_fetch_add(stats + (size_t)b * 32 + 0, ss, __ATOMIC_RELAXED,
                             __HIP_MEMORY_SCOPE_AGENT);
      __hip_atomic_fetch_add(stats + (size_t)b * 32 + 1, qq, __ATOMIC_RELAXED,
                             __HIP_MEMORY_SCOPE_AGENT);
    }
  }
  // W-pack: 4096 fragment-chunks, one per wave
  {
    const int u = blk * 4 + wave;      // 0..4095
    const int f = u & 2047;
    const int p = f >> 5, c = f & 31;
    const int r = p * 16 + l16;
    const int k0 = c * 32 + quad * 8;
    const float* wsrc = ((u >> 11) ? W2 : W1) + (size_t)r * 1024 + k0;
    float4 a0 = ((const float4*)wsrc)[0];
    float4 a1 = ((const float4*)wsrc)[1];
    float av[8] = {a0.x, a0.y, a0.z, a0.w, a1.x, a1.y, a1.z, a1.w};
    bf16x8 o;
#pragma unroll
    for (int jj = 0; jj < 8; ++jj)
      o[jj] = (short)f2bf((k0 + jj <= r) ? av[jj] : 0.f);
    unsigned short* dstp = ((u >> 11) ? W2f : W1f) +
                           ((size_t)p * 32 + c) * 512 + lane * 8;
    *(bf16x8*)dstp = o;
  }
}

// ------------- causal batched GEMM phase: pipelined LDS A, prefetched B -----
// R9-proven body (VGPR ~56 at launch_bounds(256,4) — no spill). A staged in
// 16KB quarter-panels (4 chunks), double-buffered in 32KB LDS via
// global_load_lds with hand-counted vmcnt (issue order pinned by
// sched_barrier(0)): STAGE(q)[4/thread] ... B-refills[8/quarter] ...
// STAGE(q+1)[4] => own STAGE(q) retired <=> vmcnt(12) (last: vmcnt(8)).
// Raw s_barrier; stage gate wave<rem is wave-uniform and only trims the
// LAST quarter, whose gated waves then have nothing to wait for.
template <bool HSWISH>
__device__ __forceinline__ void gemm_phase(
    unsigned short* ldsA, const int b, const int mt, unsigned* flags,
    const unsigned short* __restrict__ Af, const unsigned short* __restrict__ Bf,
    unsigned short* __restrict__ Uf, const float* __restrict__ Xres,
    float* __restrict__ Out) {
  const int t = threadIdx.x;
  const int wave = t >> 6, lane = t & 63;
  const int quad = lane >> 4, l16 = lane & 15;
  const int row0 = mt * 64;

  const int cend = 2 * (mt + 1);       // active 32-k chunks (even, 2..32)
  const int nq = (cend + 3) >> 2;      // 4-chunk quarter-panels (16KB)

  const unsigned short* Ab = Af + (size_t)mt * 4 * 32 * 512;
  const unsigned short* Bb = Bf + (size_t)b * (D_ * S_);

  spin_mask(flags, (2u << mt) - 1);    // producers of chunks 0..cend-1 done

  auto STAGE = [&](int q) {
    unsigned short* buf = ldsA + (q & 1) * 8192;
    const int c0 = q * 4;
    if (wave < cend - c0) {            // wave-uniform gate
#pragma unroll
      for (int jc = 0; jc < 4; ++jc) {
        const int flat16 = jc * 256 + t;
        async_copy16(Ab + ((size_t)jc * 32 + c0 + wave) * 512 + lane * 8,
                     buf + flat16 * 8);
      }
    }
  };

  STAGE(0);                            // oldest 4 loads/thread
  if (nq > 1) STAGE(1);                // +4
  __builtin_amdgcn_sched_barrier(0);   // pin stage-before-B issue order

  f32x4 acc[4][2] = {};
  bf16x8 Bp[4][2];
#pragma unroll
  for (int g = 0; g < 4; ++g) {        // +8 B loads (after stages)
    const int gg = (g < cend) ? g : 0;
#pragma unroll
    for (int jj = 0; jj < 2; ++jj)
      Bp[g][jj] = *(const bf16x8*)(Bb + ((size_t)(wave * 2 + jj) * 32 + gg) * 512 + lane * 8);
  }

  for (int q = 0; q < nq; ++q) {
    if (q < nq - 1)                    // T4: counted, never 0 in-loop
      asm volatile("s_waitcnt vmcnt(12)" ::: "memory");
    else
      asm volatile("s_waitcnt vmcnt(8)" ::: "memory");
    __builtin_amdgcn_s_barrier();      // all waves' STAGE(q) LDS writes done
    __builtin_amdgcn_sched_barrier(0);
    unsigned short* buf = ldsA + (q & 1) * 8192;
#pragma unroll
    for (int c = 0; c < 4; ++c) {
      const int g = q * 4 + c;
      if (g < cend) {
        bf16x8 af[4];
#pragma unroll
        for (int i = 0; i < 4; ++i)
          af[i] = *(const bf16x8*)(buf + i * 2048 + c * 512 + lane * 8);
        __builtin_amdgcn_s_setprio(1);
#pragma unroll
        for (int i = 0; i < 4; ++i)
#pragma unroll
          for (int jj = 0; jj < 2; ++jj)
            acc[i][jj] = __builtin_amdgcn_mfma_f32_16x16x32_bf16(
                af[i], Bp[c][jj], acc[i][jj], 0, 0, 0);
        __builtin_amdgcn_s_setprio(0);
      }
      const int gn = (g + 4 < cend) ? (g + 4) : 0;  // unconditional: 8/quarter
#pragma unroll
      for (int jj = 0; jj < 2; ++jj)
        Bp[c][jj] = *(const bf16x8*)(
            Bb + ((size_t)(wave * 2 + jj) * 32 + gn) * 512 + lane * 8);
    }
    __builtin_amdgcn_sched_barrier(0); // refills stay above the barrier
    __builtin_amdgcn_s_barrier();      // all waves done reading buf
    __builtin_amdgcn_sched_barrier(0);
    if (q + 2 < nq) STAGE(q + 2);      // overwrite just-freed buffer
  }

  if (HSWISH) {
    __syncthreads();                   // done with staging; reuse LDS
    unsigned short* ldsT = ldsA;       // [d][t 64 + 8 pad]
#pragma unroll
    for (int i = 0; i < 4; ++i)
#pragma unroll
      for (int jj = 0; jj < 2; ++jj) {
        ushort4 pk;
        float v0 = acc[i][jj][0], v1 = acc[i][jj][1], v2 = acc[i][jj][2], v3 = acc[i][jj][3];
        pk.x = f2bf(v0 * fminf(fmaxf(v0 + 3.f, 0.f), 6.f) * (1.f / 6.f));
        pk.y = f2bf(v1 * fminf(fmaxf(v1 + 3.f, 0.f), 6.f) * (1.f / 6.f));
        pk.z = f2bf(v2 * fminf(fmaxf(v2 + 3.f, 0.f), 6.f) * (1.f / 6.f));
        pk.w = f2bf(v3 * fminf(fmaxf(v3 + 3.f, 0.f), 6.f) * (1.f / 6.f));
        const int n = wave * 32 + jj * 16 + l16;    // d
        const int m0 = i * 16 + quad * 4;           // t within 64-tile
        *(ushort4*)(ldsT + n * 72 + m0) = pk;
      }
    __syncthreads();
    unsigned short* gU = Uf + (size_t)b * (D_ * S_);
#pragma unroll
    for (int ff = 0; ff < 4; ++ff) {
      const int f = wave * 4 + ff;
      const int p2 = f >> 1, cl = f & 1;
      const int d = p2 * 16 + l16;
      const int tb = cl * 32 + quad * 8;
      bf16x8 v = *(const bf16x8*)(ldsT + d * 72 + tb);
      store16_dev(gU + ((size_t)p2 * 32 + mt * 2 + cl) * 512 + lane * 8, v);
    }
  } else {
    float* gO = Out + (size_t)b * S_ * D_;
    const float* gX = Xres + (size_t)b * S_ * D_;
#pragma unroll
    for (int i = 0; i < 4; ++i) {
      const int mrow0 = row0 + i * 16 + quad * 4;
#pragma unroll
      for (int jj = 0; jj < 2; ++jj) {
        const int col = wave * 32 + jj * 16 + l16;
#pragma unroll
        for (int r = 0; r < 4; ++r) {
          const int addr = (mrow0 + r) * D_ + col;
          gO[addr] = gX[addr] + acc[i][jj][r];
        }
      }
    }
  }
}

// ---- K2 mega: norm -> gemm1 -> gemm2 (stats pre-published by K1) -----------
// Block (b,mt): mu/rs from K1 sums (plain loads, boundary-published) ->
// normalize own s-tile -> hTf chunks {2mt,2mt+1} via sc1 -> publish h-bit.
// gemm1 waits h-bits 0..mt, publishes u-bit; gemm2 waits u-bits 0..mt.
// 1024 blocks = 4/CU resident (32KB LDS, VGPR ~56 @ launch_bounds(256,4) —
// the proven no-spill operating point). Per-CU balance: each CU's 4 mts sum
// to 68 chunk-iters in both gemm phases.
__global__ __launch_bounds__(256, 4) void mega_kernel(
    const float* __restrict__ x, const float* __restrict__ ln_w,
    const float* __restrict__ ln_b, const unsigned short* __restrict__ W1f,
    const unsigned short* __restrict__ W2f, float* __restrict__ stats,
    unsigned short* __restrict__ hTf, unsigned short* __restrict__ uTf,
    float* __restrict__ out) {
  __shared__ __align__(16) unsigned short smem[16384];   // 32 KB, all phases

  const int bi = blockIdx.x;           // 0..1023
  const int xcd = bi & 7;              // perf heuristic only (L2 locality)
  const int slot = bi >> 3;
  const int b = xcd * 8 + (slot & 7);
  const int j = slot >> 3;
  const int mt = (j < 8) ? j : (j ^ 3);

  const int t = threadIdx.x;
  const int wave = t >> 6, lane = t & 63;
  const int quad = lane >> 4, l16 = lane & 15;

  float* sb = stats + (size_t)b * 32;  // 128B/batch slot
  unsigned* hmp = (unsigned*)sb + 4;
  unsigned* ump = (unsigned*)sb + 6;

  // ---------- mu/rs from K1-published sums (no spin, no x-pass) -------------
  const float inv = 1.0f / (S_ * D_);
  const float mu = sb[0] * inv;
  const float rs = rsqrtf(sb[1] * inv - mu * mu + 1e-5f);

  // ---------- normalize own s-tile + LDS [s][d+4pad] transpose --------------
  {
    unsigned short* lds = smem;
    const float4* xb = (const float4*)(x + ((size_t)b * S_ + mt * 64) * D_);
    const float4* wb = (const float4*)(ln_w + (size_t)(mt * 64) * D_);
    const float4* bv4 = (const float4*)(ln_b + (size_t)(mt * 64) * D_);
#pragma unroll
    for (int rr = 0; rr < 8; ++rr) {
      const int f = rr * 256 + t;
      const int srow = f >> 5;
      const int c4 = f & 31;
      float4 xv = xb[f];
      float4 wv = wb[f];
      float4 bvv = bv4[f];
      ushort4 o;
      o.x = f2bf((xv.x - mu) * rs * wv.x + bvv.x);
      o.y = f2bf((xv.y - mu) * rs * wv.y + bvv.y);
      o.z = f2bf((xv.z - mu) * rs * wv.z + bvv.z);
      o.w = f2bf((xv.w - mu) * rs * wv.w + bvv.w);
      *(ushort4*)(lds + srow * 132 + c4 * 4) = o;
    }
    __syncthreads();
    unsigned short* outp = hTf + (size_t)b * (D_ * S_);
    const int cg0 = mt * 2;
#pragma unroll
    for (int ff = 0; ff < 4; ++ff) {
      const int f = wave * 4 + ff;     // 16 fragments per block
      const int p = f >> 1, cl = f & 1;
      const int d = p * 16 + l16;
      const int sbase = cl * 32 + quad * 8;
      bf16x8 v;
#pragma unroll
      for (int jj = 0; jj < 8; ++jj)
        v[jj] = (short)lds[(sbase + jj) * 132 + d];
      store16_dev(outp + ((size_t)p * 32 + cg0 + cl) * 512 + lane * 8, v);
    }
  }
  publish_bit(hmp, 1u << mt);

  // ---------- gemm1: u = hardswish(W1c @ h) ---------------------------------
  gemm_phase<true>(smem, b, mt, hmp, W1f, hTf, uTf, nullptr, nullptr);
  publish_bit(ump, 1u << mt);

  // ---------- gemm2: out = x + W2c @ u --------------------------------------
  gemm_phase<false>(smem, b, mt, ump, W2f, uTf, nullptr, x, out);
}

extern "C" void kernel_launch(void* const* d_in, const int* in_sizes, int n_in,
                              void* d_out, int out_size, void* d_ws, size_t ws_size,
                              hipStream_t stream) {
  const float* x = (const float*)d_in[0];
  const float* ln_w = (const float*)d_in[1];
  const float* ln_b = (const float*)d_in[2];
  const float* W1 = (const float*)d_in[3];
  const float* W2 = (const float*)d_in[4];
  float* out = (float*)d_out;

  char* ws = (char*)d_ws;
  float* stats = (float*)ws;                                 // 8 KiB (64x128B)
  unsigned short* W1f = (unsigned short*)(ws + 16384);       // 2 MiB
  unsigned short* W2f = W1f + (size_t)S_ * S_;               // 2 MiB
  unsigned short* hTf = W2f + (size_t)S_ * S_;               // 16 MiB
  unsigned short* uTf = hTf + (size_t)NB * D_ * S_;          // 16 MiB

  hipMemsetAsync(stats, 0, 8192, stream);   // zero stats/flag slots
  prep_kernel<<<1024, 256, 0, stream>>>(x, W1, W2, stats, W1f, W2f);
  mega_kernel<<<1024, 256, 0, stream>>>(x, ln_w, ln_b, W1f, W2f, stats,
                                        hTf, uTf, out);
}